// Round 1
// baseline (20041.133 us; speedup 1.0000x reference)
//
#include <hip/hip_runtime.h>
#include <cmath>

#define NMAT 64
#define LDA  65          // +1 pad: column access banks (i + c) % 32 -> 2-way (free)
#define SWEEPS 12
#define TPB  256
#define NTRI 2080        // 64*65/2

__device__ __forceinline__ void pair_of(int r, int k, int* p, int* q) {
    // circle-method round robin: round r (0..62), pair k (0..31)
    if (k == 0) { *p = 63; *q = r; }
    else {
        *p = (r + k) % 63;
        *q = (r - k + 63) % 63;
    }
}

__global__ __launch_bounds__(TPB) void spd_logm_kernel(const float* __restrict__ in,
                                                       float* __restrict__ out,
                                                       int nmat_total) {
    __shared__ float A[NMAT * LDA];
    __shared__ float V[NMAT * LDA];
    __shared__ float c_arr[32];
    __shared__ float s_arr[32];
    __shared__ float lw[NMAT];

    const int b = blockIdx.x;
    if (b >= nmat_total) return;
    const int t = threadIdx.x;
    const float* __restrict__ Ain = in + (size_t)b * NMAT * NMAT;

    // ---- load A (coalesced), init V = I ----
    for (int e = t; e < NMAT * NMAT; e += TPB) {
        int i = e >> 6, j = e & 63;
        A[i * LDA + j] = Ain[e];
        V[i * LDA + j] = (i == j) ? 1.0f : 0.0f;
    }
    __syncthreads();

    // ---- parallel Jacobi sweeps ----
    for (int sweep = 0; sweep < SWEEPS; ++sweep) {
        for (int r = 0; r < 63; ++r) {
            // 1) rotation angles for the 32 disjoint pairs
            if (t < 32) {
                int p, q; pair_of(r, t, &p, &q);
                float app = A[p * LDA + p];
                float aqq = A[q * LDA + q];
                float apq = A[p * LDA + q];
                float cc = 1.0f, ss = 0.0f;
                if (apq != 0.0f) {
                    float tau = (aqq - app) / (2.0f * apq);
                    float tt  = copysignf(1.0f / (fabsf(tau) + sqrtf(1.0f + tau * tau)), tau);
                    cc = 1.0f / sqrtf(1.0f + tt * tt);
                    ss = tt * cc;
                }
                c_arr[t] = cc;
                s_arr[t] = ss;
            }
            __syncthreads();

            // 2) row phase: B = J^T A   (pair k rotates rows p,q; consecutive lanes -> consecutive j)
            for (int it = t; it < 32 * NMAT; it += TPB) {
                int k = it >> 6, j = it & 63;
                int p, q; pair_of(r, k, &p, &q);
                float cc = c_arr[k], ss = s_arr[k];
                float x = A[p * LDA + j];
                float y = A[q * LDA + j];
                A[p * LDA + j] = cc * x - ss * y;
                A[q * LDA + j] = ss * x + cc * y;
            }
            __syncthreads();

            // 3) col phase: A = B J, fused with V = V J
            for (int it = t; it < 32 * NMAT; it += TPB) {
                int k = it >> 6, i = it & 63;
                int p, q; pair_of(r, k, &p, &q);
                float cc = c_arr[k], ss = s_arr[k];
                float x = A[i * LDA + p];
                float y = A[i * LDA + q];
                A[i * LDA + p] = cc * x - ss * y;
                A[i * LDA + q] = ss * x + cc * y;
                float vx = V[i * LDA + p];
                float vy = V[i * LDA + q];
                V[i * LDA + p] = cc * vx - ss * vy;
                V[i * LDA + q] = ss * vx + cc * vy;
            }
            __syncthreads();
        }
    }

    // ---- epilogue: logm = V diag(log w) V^T, upper triangle row-major ----
    if (t < NMAT) {
        lw[t] = logf(fmaxf(A[t * LDA + t], 1e-30f));
    }
    __syncthreads();
    // W = V * diag(lw), stored into A
    for (int e = t; e < NMAT * NMAT; e += TPB) {
        int i = e >> 6, k = e & 63;
        A[i * LDA + k] = V[i * LDA + k] * lw[k];
    }
    __syncthreads();

    float* __restrict__ outb = out + (size_t)b * NTRI;
    for (int o = t; o < NTRI; o += TPB) {
        // row index from linear upper-tri offset: off(i) = i*(129-i)/2
        int i = (int)((129.0f - sqrtf(16641.0f - 8.0f * (float)o)) * 0.5f);
        while (i > 0 && i * (129 - i) / 2 > o) --i;
        while ((i + 1) * (129 - (i + 1)) / 2 <= o) ++i;
        int j = i + (o - i * (129 - i) / 2);

        const float* __restrict__ wa = &A[i * LDA];
        const float* __restrict__ vb = &V[j * LDA];
        float acc = 0.0f;
        #pragma unroll
        for (int k = 0; k < NMAT; ++k) acc += wa[k] * vb[k];
        outb[o] = acc;
    }
}

extern "C" void kernel_launch(void* const* d_in, const int* in_sizes, int n_in,
                              void* d_out, int out_size, void* d_ws, size_t ws_size,
                              hipStream_t stream) {
    const float* in = (const float*)d_in[0];
    float* out = (float*)d_out;
    int nmat = in_sizes[0] / (NMAT * NMAT);   // 8192
    spd_logm_kernel<<<nmat, TPB, 0, stream>>>(in, out, nmat);
}

// Round 2
// 10575.670 us; speedup vs baseline: 1.8950x; 1.8950x over previous
//
#include <hip/hip_runtime.h>
#include <cmath>

#define NMAT 64
#define LDA  65          // odd stride: row AND column access both conflict-free (2-way)
#define SWEEPS 9
#define TPB  256
#define NTRI 2080        // 64*65/2

__device__ __forceinline__ float bcast_lane(float v, int l) {
    return __uint_as_float(__builtin_amdgcn_readlane(__float_as_uint(v), l));
}

// circle-method round robin: round r (0..62), pair k (0..31); branch-free-ish selects
__device__ __forceinline__ void pair_pq(int r, int k, int& p, int& q) {
    if (k == 0) { p = 63; q = r; }
    else {
        int a = r + k;  p = (a >= 63) ? a - 63 : a;
        int b = r - k;  q = (b < 0)   ? b + 63 : b;
    }
}

__global__ __launch_bounds__(TPB) void spd_logm_kernel(const float* __restrict__ in,
                                                       float* __restrict__ out) {
    __shared__ float A[NMAT * LDA];
    __shared__ float V[NMAT * LDA];
    __shared__ float lw[NMAT];

    const int b    = blockIdx.x;
    const int t    = threadIdx.x;
    const int w    = t >> 6;      // wave id 0..3
    const int lane = t & 63;
    const float* __restrict__ Ain = in + (size_t)b * (NMAT * NMAT);

    // ---- load A (float4 coalesced), init V = I ----
    for (int e4 = t; e4 < NMAT * NMAT / 4; e4 += TPB) {
        float4 v = ((const float4*)Ain)[e4];
        int i = e4 >> 4, j = (e4 & 15) * 4;
        float* dst = &A[i * LDA + j];
        dst[0] = v.x; dst[1] = v.y; dst[2] = v.z; dst[3] = v.w;
        float* vd = &V[i * LDA + j];
        vd[0] = (i == j + 0) ? 1.f : 0.f;
        vd[1] = (i == j + 1) ? 1.f : 0.f;
        vd[2] = (i == j + 2) ? 1.f : 0.f;
        vd[3] = (i == j + 3) ? 1.f : 0.f;
    }
    __syncthreads();

    for (int sweep = 0; sweep < SWEEPS; ++sweep) {
      for (int r = 0; r < 63; ++r) {
        // ---- angles for this wave's 8 pairs, computed in lanes 0..7 ----
        // Race-free without a barrier: reads touch only rows/cols of each pair's
        // own {p,q}, and the 32 pairs partition 0..63 (disjoint across waves).
        float cv = 1.f, sv = 0.f;
        if (lane < 8) {
            int p, q; pair_pq(r, w * 8 + lane, p, q);
            float app = A[p * LDA + p];
            float aqq = A[q * LDA + q];
            float apq = A[p * LDA + q];
            float tau = (aqq - app) / (2.f * apq);
            float den = fabsf(tau) + sqrtf(fmaf(tau, tau, 1.f));
            float tt  = copysignf(1.f / den, tau);
            tt = (apq == 0.f) ? 0.f : tt;           // also kills the 0/0=NaN case
            cv = 1.f / sqrtf(fmaf(tt, tt, 1.f));
            sv = tt * cv;
        }

        // ---- row phase: wave w rotates rows of pairs k = 8w..8w+7 ----
        #pragma unroll
        for (int l = 0; l < 8; ++l) {
            int p, q; pair_pq(r, w * 8 + l, p, q);   // wave-uniform -> SALU
            float c = bcast_lane(cv, l), s = bcast_lane(sv, l);
            float* rp = &A[p * LDA + lane];
            float* rq = &A[q * LDA + lane];
            float x = *rp, y = *rq;
            *rp = c * x - s * y;
            *rq = s * x + c * y;
        }
        __syncthreads();

        // ---- col phase on A, fused with V accumulation ----
        #pragma unroll
        for (int l = 0; l < 8; ++l) {
            int p, q; pair_pq(r, w * 8 + l, p, q);
            float c = bcast_lane(cv, l), s = bcast_lane(sv, l);
            float* cp = &A[lane * LDA + p];
            float* cq = &A[lane * LDA + q];
            float x = *cp, y = *cq;
            *cp = c * x - s * y;
            *cq = s * x + c * y;
            float* vp = &V[lane * LDA + p];
            float* vq = &V[lane * LDA + q];
            float vx = *vp, vy = *vq;
            *vp = c * vx - s * vy;
            *vq = s * vx + c * vy;
        }
        __syncthreads();
      }
    }

    // ---- epilogue: logm = V diag(log w) V^T, upper triangle row-major ----
    if (t < NMAT) {
        lw[t] = logf(fmaxf(A[t * LDA + t], 1e-30f));
    }
    __syncthreads();
    for (int e = t; e < NMAT * NMAT; e += TPB) {
        int i = e >> 6, k = e & 63;
        A[i * LDA + k] = V[i * LDA + k] * lw[k];   // A <- V * diag(lw)
    }
    __syncthreads();

    float* __restrict__ outb = out + (size_t)b * NTRI;
    for (int o = t; o < NTRI; o += TPB) {
        // row index from linear upper-tri offset: off(i) = i*(129-i)/2
        int i = (int)((129.0f - sqrtf(16641.0f - 8.0f * (float)o)) * 0.5f);
        while (i > 0 && i * (129 - i) / 2 > o) --i;
        while ((i + 1) * (129 - (i + 1)) / 2 <= o) ++i;
        int j = i + (o - i * (129 - i) / 2);

        const float* __restrict__ wa = &A[i * LDA];
        const float* __restrict__ vb = &V[j * LDA];
        float acc = 0.0f;
        #pragma unroll
        for (int k = 0; k < NMAT; ++k) acc += wa[k] * vb[k];
        outb[o] = acc;
    }
}

extern "C" void kernel_launch(void* const* d_in, const int* in_sizes, int n_in,
                              void* d_out, int out_size, void* d_ws, size_t ws_size,
                              hipStream_t stream) {
    const float* in = (const float*)d_in[0];
    float* out = (float*)d_out;
    int nmat = in_sizes[0] / (NMAT * NMAT);   // 8192
    spd_logm_kernel<<<nmat, TPB, 0, stream>>>(in, out);
}

// Round 3
// 8838.469 us; speedup vs baseline: 2.2675x; 1.1965x over previous
//
#include <hip/hip_runtime.h>
#include <cmath>

#define NMAT 64
#define LDA  65            // odd stride: row & col phases both 2-way bank aliasing (free)
#define SWEEPS 7
#define TPB  256
#define NTRI 2080          // 64*65/2
#define VOFF (NMAT * LDA)  // V lives right after A -> 16640-byte ds offset immediate

__device__ __forceinline__ float bcast_lane(float v, int l) {
    return __uint_as_float(__builtin_amdgcn_readlane(__float_as_uint(v), l));
}
__device__ __forceinline__ int rfl(int x) { return __builtin_amdgcn_readfirstlane(x); }

// circle-method round robin: round r (0..62), pair k (0..31)
// With r,k wave-uniform SGPRs this is pure SALU (s_cselect).
__device__ __forceinline__ void pair_pq(int r, int k, int& p, int& q) {
    if (k == 0) { p = 63; q = r; }
    else {
        int a = r + k;  p = (a >= 63) ? a - 63 : a;
        int b = r - k;  q = (b < 0)   ? b + 63 : b;
    }
}

__global__ __launch_bounds__(TPB) void spd_logm_kernel(const float* __restrict__ in,
                                                       float* __restrict__ out) {
    __shared__ float S[2 * NMAT * LDA];    // [A | V] contiguous
    __shared__ float lw[NMAT];
    float* __restrict__ A = S;
    float* __restrict__ V = S + VOFF;

    const int b    = blockIdx.x;
    const int t    = threadIdx.x;
    const int lane = t & 63;
    const int w    = rfl(t >> 6);          // FORCE wave id into SGPR: p,q/addr math -> SALU
    const float* __restrict__ Ain = in + (size_t)b * (NMAT * NMAT);

    // ---- load A (float4 coalesced), init V = I ----
    for (int e4 = t; e4 < NMAT * NMAT / 4; e4 += TPB) {
        float4 v = ((const float4*)Ain)[e4];
        int i = e4 >> 4, j = (e4 & 15) * 4;
        float* dst = &A[i * LDA + j];
        dst[0] = v.x; dst[1] = v.y; dst[2] = v.z; dst[3] = v.w;
        float* vd = &V[i * LDA + j];
        vd[0] = (i == j + 0) ? 1.f : 0.f;
        vd[1] = (i == j + 1) ? 1.f : 0.f;
        vd[2] = (i == j + 2) ? 1.f : 0.f;
        vd[3] = (i == j + 3) ? 1.f : 0.f;
    }
    __syncthreads();

    // per-lane LDS bases (VGPR), reused every round
    float* __restrict__ rowbase = &S[lane];           // + p*LDA (SGPR) -> row phase addr
    float* __restrict__ colbase = &S[lane * LDA];     // + p (SGPR) -> col phase addr; +VOFF imm -> V

    for (int sweep = 0; sweep < SWEEPS; ++sweep) {
      for (int r = 0; r < 63; ++r) {
        // ---- angles for this wave's 8 pairs, lanes 0..7 (no barrier needed:
        // reads only {p,q} rows/cols of this wave's own pairs, disjoint across waves) ----
        float cv = 1.f, sv = 0.f;
        if (lane < 8) {
            int p, q; pair_pq(r, w * 8 + lane, p, q);  // divergent here: VGPR, fine (8 lanes)
            float app = A[p * LDA + p];
            float aqq = A[q * LDA + q];
            float apq = A[p * LDA + q];
            float tau = (aqq - app) / (2.f * apq);
            float den = fabsf(tau) + sqrtf(fmaf(tau, tau, 1.f));
            float tt  = copysignf(1.f / den, tau);
            tt = (apq == 0.f) ? 0.f : tt;
            cv = 1.f / sqrtf(fmaf(tt, tt, 1.f));
            sv = tt * cv;
        }

        // ---- row phase: B = J^T A ----
        #pragma unroll
        for (int l = 0; l < 8; ++l) {
            int p, q; pair_pq(r, w * 8 + l, p, q);     // SGPR -> SALU
            float c = bcast_lane(cv, l), s = bcast_lane(sv, l);
            float* rp = rowbase + p * LDA;             // vbase + SGPR: 1 v_add
            float* rq = rowbase + q * LDA;
            float x = *rp, y = *rq;
            *rp = c * x - s * y;
            *rq = s * x + c * y;
        }
        __syncthreads();

        // ---- col phase: A = B J, fused V = V J (V via offset immediate) ----
        #pragma unroll
        for (int l = 0; l < 8; ++l) {
            int p, q; pair_pq(r, w * 8 + l, p, q);     // SGPR -> SALU
            float c = bcast_lane(cv, l), s = bcast_lane(sv, l);
            float* cp = colbase + p;                   // 1 v_add; V access = same addr + imm
            float* cq = colbase + q;
            float x = cp[0], y = cq[0];
            cp[0] = c * x - s * y;
            cq[0] = s * x + c * y;
            float vx = cp[VOFF], vy = cq[VOFF];
            cp[VOFF] = c * vx - s * vy;
            cq[VOFF] = s * vx + c * vy;
        }
        __syncthreads();
      }
    }

    // ---- epilogue: logm = V diag(log w) V^T, upper triangle row-major ----
    if (t < NMAT) {
        lw[t] = logf(fmaxf(A[t * LDA + t], 1e-30f));
    }
    __syncthreads();
    for (int e = t; e < NMAT * NMAT; e += TPB) {
        int i = e >> 6, k = e & 63;
        A[i * LDA + k] = V[i * LDA + k] * lw[k];       // A <- V * diag(lw)
    }
    __syncthreads();

    float* __restrict__ outb = out + (size_t)b * NTRI;
    for (int o = t; o < NTRI; o += TPB) {
        int i = (int)((129.0f - sqrtf(16641.0f - 8.0f * (float)o)) * 0.5f);
        while (i > 0 && i * (129 - i) / 2 > o) --i;
        while ((i + 1) * (129 - (i + 1)) / 2 <= o) ++i;
        int j = i + (o - i * (129 - i) / 2);

        const float* __restrict__ wa = &A[i * LDA];
        const float* __restrict__ vb = &V[j * LDA];
        float acc = 0.0f;
        #pragma unroll
        for (int k = 0; k < NMAT; ++k) acc += wa[k] * vb[k];
        outb[o] = acc;
    }
}

extern "C" void kernel_launch(void* const* d_in, const int* in_sizes, int n_in,
                              void* d_out, int out_size, void* d_ws, size_t ws_size,
                              hipStream_t stream) {
    const float* in = (const float*)d_in[0];
    float* out = (float*)d_out;
    int nmat = in_sizes[0] / (NMAT * NMAT);   // 8192
    spd_logm_kernel<<<nmat, TPB, 0, stream>>>(in, out);
}

// Round 4
// 6082.622 us; speedup vs baseline: 3.2948x; 1.4531x over previous
//
#include <hip/hip_runtime.h>
#include <cmath>

#define TPB    256
#define SWEEPS 7
#define NTRI   2080     // 64*65/2

// butterfly add within 16-lane groups (xor masks 1,2,4,8 — intra-32, guide-verified patterns)
#define SWZ(v, pat) __uint_as_float(__builtin_amdgcn_ds_swizzle(__float_as_uint(v), pat))

__device__ __forceinline__ int rfl(int x) { return __builtin_amdgcn_readfirstlane(x); }

__device__ __forceinline__ float4 f4rot(float4 a, float4 b, float c, float s) {
    // c*a - s*b componentwise
    float4 r;
    r.x = c * a.x - s * b.x;  r.y = c * a.y - s * b.y;
    r.z = c * a.z - s * b.z;  r.w = c * a.w - s * b.w;
    return r;
}

__global__ __launch_bounds__(TPB) void spd_logm_kernel(const float* __restrict__ in,
                                                       float* __restrict__ out) {
    __shared__ float Wb[64 * 64];     // A -> Cholesky L (rows = one-sided Jacobi vectors) -> scaled VT
    __shared__ float VT[64 * 64];     // VT[k][i] = V[i][k], rows rotate like W rows
    __shared__ float norms[64];       // row squared norms (-> eigenvalues -> log)

    const int b    = blockIdx.x;
    const int t    = threadIdx.x;
    const int lane = t & 63;
    const int w    = rfl(t >> 6);     // wave id in SGPR
    const int g    = lane >> 4;       // 16-lane group 0..3
    const int u    = lane & 15;
    const int u4   = u << 2;

    // ---- load A into Wb (b128), VT = I ----
    const float4* __restrict__ in4 = (const float4*)(in + (size_t)b * 4096);
    for (int e = t; e < 1024; e += TPB) ((float4*)Wb)[e] = in4[e];
    for (int e = t; e < 1024; e += TPB) {
        int r = e >> 4, c0 = (e & 15) << 2;
        float4 v;
        v.x = (r == c0 + 0) ? 1.f : 0.f;  v.y = (r == c0 + 1) ? 1.f : 0.f;
        v.z = (r == c0 + 2) ? 1.f : 0.f;  v.w = (r == c0 + 3) ? 1.f : 0.f;
        ((float4*)VT)[e] = v;
    }
    __syncthreads();

    // norms[k] = ||L row k||^2 = (L L^T)[k][k] = A[k][k] exactly: save diag BEFORE Cholesky
    if (t < 64) norms[t] = Wb[t * 64 + t];
    __syncthreads();

    // ---- Cholesky in place (lower triangle; upper zeroed after) ----
    for (int k = 0; k < 64; ++k) {
        if (w == 0) {                                  // scale column k
            float wkk = Wb[k * 64 + k];
            float rd  = __builtin_amdgcn_rsqf(wkk);    // SPD: wkk >= 1e-3
            Wb[lane * 64 + k] = Wb[lane * 64 + k] * rd;
        }
        __syncthreads();
        float ck = Wb[lane * 64 + k];                  // scaled col k, element 'lane'
        for (int i = k + 1 + w; i < 64; i += 4) {      // trailing update, rows wave-strided
            float aik = __shfl(ck, i, 64);             // i is SGPR -> readlane
            if (lane > k) Wb[i * 64 + lane] -= aik * ck;
        }
        __syncthreads();
    }
    // zero strict upper of W
    for (int e = t; e < 4096; e += TPB) {
        int r = e >> 6, c = e & 63;
        if (c > r) Wb[e] = 0.f;
    }
    __syncthreads();

    // ---- one-sided Jacobi sweeps, XOR schedule: round m pairs p <-> p^m ----
    for (int sweep = 0; sweep < SWEEPS; ++sweep) {
      for (int m = 1; m < 64; ++m) {
        int h = 31 - __clz(m);              // uniform (SGPR)
        int lomask = (1 << h) - 1;
        #pragma unroll
        for (int it = 0; it < 2; ++it) {
            int k = w * 8 + it * 4 + g;     // pair id 0..31, group-uniform
            int p = ((k & ~lomask) << 1) | (k & lomask);   // k with 0 inserted at bit h
            int q = p ^ m;                                  // > p
            float4 wp = *(float4*)&Wb[(p << 6) + u4];
            float4 wq = *(float4*)&Wb[(q << 6) + u4];
            // apq = <w_p, w_q> via 16-lane butterfly
            float apq = wp.x * wq.x + wp.y * wq.y + wp.z * wq.z + wp.w * wq.w;
            apq += SWZ(apq, 0x041F);
            apq += SWZ(apq, 0x081F);
            apq += SWZ(apq, 0x101F);
            apq += SWZ(apq, 0x201F);
            float app = norms[p], aqq = norms[q];
            // Jacobi angle (approx rcp/rsq fine for rotation params)
            float tau = (aqq - app) * 0.5f * __builtin_amdgcn_rcpf(apq);
            float den = fabsf(tau) + sqrtf(fmaf(tau, tau, 1.f));
            float tt  = copysignf(__builtin_amdgcn_rcpf(den), tau);
            tt = (fabsf(apq) < 1e-35f) ? 0.f : tt;          // tiny/zero apq -> identity
            float c = __builtin_amdgcn_rsqf(fmaf(tt, tt, 1.f));
            float s = tt * c;
            // rotate W rows p,q
            *(float4*)&Wb[(p << 6) + u4] = f4rot(wp, wq, c, s);
            *(float4*)&Wb[(q << 6) + u4] = f4rot(wq, wp, c, -s);
            // rotate VT rows p,q
            float4 vp = *(float4*)&VT[(p << 6) + u4];
            float4 vq = *(float4*)&VT[(q << 6) + u4];
            *(float4*)&VT[(p << 6) + u4] = f4rot(vp, vq, c, s);
            *(float4*)&VT[(q << 6) + u4] = f4rot(vq, vp, c, -s);
            // analytic norm update (exact recompute after sweeps)
            if (u == 0) {
                norms[p] = fmaf(-tt, apq, app);
                norms[q] = fmaf( tt, apq, aqq);
            }
        }
        __syncthreads();                    // ONE barrier per round
      }
    }

    // ---- exact eigenvalues: recompute row norms, then log in place ----
    #pragma unroll
    for (int it = 0; it < 4; ++it) {
        int r = w * 16 + it * 4 + g;
        float4 x = *(float4*)&Wb[(r << 6) + u4];
        float nn = x.x * x.x + x.y * x.y + x.z * x.z + x.w * x.w;
        nn += SWZ(nn, 0x041F);
        nn += SWZ(nn, 0x081F);
        nn += SWZ(nn, 0x101F);
        nn += SWZ(nn, 0x201F);
        if (u == 0) norms[r] = nn;
    }
    __syncthreads();
    if (t < 64) norms[t] = logf(norms[t]);
    __syncthreads();

    // ---- Wb <- VT scaled by lw[k] rowwise (SVT[k][i] = VT[k][i]*lw[k]) ----
    for (int e = t; e < 1024; e += TPB) {
        int kk = e >> 4;
        float lwk = norms[kk];
        float4 v = ((float4*)VT)[e];
        v.x *= lwk; v.y *= lwk; v.z *= lwk; v.w *= lwk;
        ((float4*)Wb)[e] = v;
    }
    __syncthreads();

    // ---- upper-tri output: logm[i][j] = sum_k SVT[k][i] * VT[k][j] ----
    float* __restrict__ outb = out + (size_t)b * NTRI;
    for (int o = t; o < NTRI; o += TPB) {
        int i = (int)((129.0f - sqrtf(16641.0f - 8.0f * (float)o)) * 0.5f);
        while (i > 0 && i * (129 - i) / 2 > o) --i;
        while ((i + 1) * (129 - (i + 1)) / 2 <= o) ++i;
        int j = i + (o - i * (129 - i) / 2);

        const float* __restrict__ wa = Wb + i;   // SVT column i: stride-64, same-addr broadcast across lanes
        const float* __restrict__ vb = VT + j;
        float acc = 0.0f;
        #pragma unroll
        for (int k = 0; k < 64; ++k) acc = fmaf(wa[k << 6], vb[k << 6], acc);
        outb[o] = acc;
    }
}

extern "C" void kernel_launch(void* const* d_in, const int* in_sizes, int n_in,
                              void* d_out, int out_size, void* d_ws, size_t ws_size,
                              hipStream_t stream) {
    const float* in = (const float*)d_in[0];
    float* out = (float*)d_out;
    int nmat = in_sizes[0] / 4096;    // 8192
    spd_logm_kernel<<<nmat, TPB, 0, stream>>>(in, out);
}

// Round 6
// 3781.611 us; speedup vs baseline: 5.2996x; 1.6085x over previous
//
#include <hip/hip_runtime.h>
#include <cmath>

#define TPB    256
#define SWEEPS 7
#define NTRI   2080      // 64*65/2
#define LDW    68        // row stride in floats: staggers bank phases, 16B-aligned rows

// 21 XOR-closed triples {b1, b2, b1^b2} covering masks 1..63 (GF(64) {1,w,w^2} cosets),
// stored as reduced basis (b1,h1=msb(b1), b2,h2=msb(b2), b1 bit-h2 cleared).
__constant__ int TB1[21] = {58,53,41,17,34,32,13,26,52,43,37,35,18,36,20,40,44,38,54,47,33};
__constant__ int TH1[21] = { 5, 5, 5, 4, 5, 5, 3, 4, 5, 5, 5, 5, 4, 5, 4, 5, 5, 5, 5, 5, 5};
__constant__ int TB2[21] = { 1, 2, 4, 8,16, 7, 3, 6,12,24,21, 9, 5,10,11,22,19,27,15,30,29};
__constant__ int TH2[21] = { 0, 1, 2, 3, 4, 2, 1, 2, 3, 4, 4, 3, 2, 3, 3, 4, 4, 4, 3, 4, 4};

__device__ __forceinline__ int rfl(int x) { return __builtin_amdgcn_readfirstlane(x); }

template<int CTRL>
__device__ __forceinline__ float dppf(float x) {
    return __int_as_float(__builtin_amdgcn_update_dpp(0, __float_as_int(x), CTRL, 0xf, 0xf, true));
}
// sum across the 16-lane DPP row, result broadcast to all 16 lanes (pure VALU)
__device__ __forceinline__ float red16(float x) {
    x += dppf<0x124>(x);   // row_ror:4
    x += dppf<0x128>(x);   // row_ror:8
    x += dppf<0xB1>(x);    // quad_perm [1,0,3,2]
    x += dppf<0x4E>(x);    // quad_perm [2,3,0,1]
    return x;
}

__device__ __forceinline__ float4 f4rot(float4 a, float4 b, float c, float s) {
    float4 r;
    r.x = c * a.x - s * b.x;  r.y = c * a.y - s * b.y;
    r.z = c * a.z - s * b.z;  r.w = c * a.w - s * b.w;
    return r;
}

// One Jacobi rotation on register-resident rows (W pair + VT pair + Gram-diag pair).
// Same angle/update math as the R4-verified kernel.
__device__ __forceinline__ void jrot(float4& wp, float4& wq, float4& vp, float4& vq,
                                     float& np, float& nq) {
    float apq = red16(wp.x * wq.x + wp.y * wq.y + wp.z * wq.z + wp.w * wq.w);
    float tau = (nq - np) * 0.5f * __builtin_amdgcn_rcpf(apq);
    float den = fabsf(tau) + sqrtf(fmaf(tau, tau, 1.f));
    float tt  = copysignf(__builtin_amdgcn_rcpf(den), tau);
    tt = (fabsf(apq) < 1e-30f) ? 0.f : tt;
    float c = __builtin_amdgcn_rsqf(fmaf(tt, tt, 1.f));
    float s = tt * c;
    float4 wa = wp, wb = wq;
    wp = f4rot(wa, wb, c, s);
    wq = f4rot(wb, wa, c, -s);
    float4 va = vp, vb = vq;
    vp = f4rot(va, vb, c, s);
    vq = f4rot(vb, va, c, -s);
    np = fmaf(-tt, apq, np);
    nq = fmaf( tt, apq, nq);
}

__global__ __launch_bounds__(TPB) void spd_logm_kernel(const float* __restrict__ in,
                                                       float* __restrict__ out) {
    __shared__ float S[2 * 64 * LDW];   // [ W | VT ]
    __shared__ float norms[64];
    float* __restrict__ Wb = S;
    float* __restrict__ VT = S + 64 * LDW;

    const int b    = blockIdx.x;
    const int t    = threadIdx.x;
    const int lane = t & 63;
    const int w    = rfl(t >> 6);   // wave id (SGPR), used in Cholesky
    const int G    = t >> 4;        // 16-lane group id 0..15 (one 4-row coset per group)
    const int u    = t & 15;
    const int u4   = u << 2;

    // ---- load A (b128 coalesced), VT = I ----
    const float4* __restrict__ in4 = (const float4*)(in + (size_t)b * 4096);
    for (int e = t; e < 1024; e += TPB) {
        int row = e >> 4, col = (e & 15) << 2;
        *(float4*)&Wb[row * LDW + col] = in4[e];
        float4 v;
        v.x = (row == col + 0) ? 1.f : 0.f;  v.y = (row == col + 1) ? 1.f : 0.f;
        v.z = (row == col + 2) ? 1.f : 0.f;  v.w = (row == col + 3) ? 1.f : 0.f;
        *(float4*)&VT[row * LDW + col] = v;
    }
    __syncthreads();

    // ---- Cholesky in place (R4-verified; LDW pad cuts col-access conflicts 32->8 way) ----
    for (int k = 0; k < 64; ++k) {
        if (w == 0) {
            float wkk = Wb[k * LDW + k];
            float rd  = __builtin_amdgcn_rsqf(wkk);    // SPD: wkk >= ~1e-3
            Wb[lane * LDW + k] *= rd;
        }
        __syncthreads();
        float ck = Wb[lane * LDW + k];
        for (int i = k + 1 + w; i < 64; i += 4) {
            float aik = __shfl(ck, i, 64);
            if (lane > k) Wb[i * LDW + lane] -= aik * ck;
        }
        __syncthreads();
    }
    for (int e = t; e < 4096; e += TPB) {              // zero strict upper
        int r = e >> 6, c = e & 63;
        if (c > r) Wb[r * LDW + c] = 0.f;
    }
    __syncthreads();

    // ---- one-sided Jacobi on rows of L (Gram = LL^T = A, kappa ~ 4e3: fp32-safe) ----
    for (int sweep = 0; sweep < SWEEPS; ++sweep) {
        // exact Gram-diag (row norm^2) refresh
        #pragma unroll
        for (int i = 0; i < 4; ++i) {
            int r = (G << 2) + i;
            float4 x = *(float4*)&Wb[r * LDW + u4];
            float nn = red16(x.x * x.x + x.y * x.y + x.z * x.z + x.w * x.w);
            if (u == 0) norms[r] = nn;
        }
        __syncthreads();

        // 21 macro-rounds; each = 3 XOR-schedule rounds fused inside 4-row cosets
        for (int j = 0; j < 21; ++j) {
            const int b1 = TB1[j], h1 = TH1[j], b2 = TB2[j], h2 = TH2[j];
            // coset representative: insert 0-bits at h2 then h1 into group index G
            int m  = (G & ((1 << h2) - 1)) | ((G >> h2) << (h2 + 1));
            int rp = (m & ((1 << h1) - 1)) | ((m >> h1) << (h1 + 1));
            const int z0 = rp, z1 = rp ^ b1, z2 = rp ^ b2, z3 = z1 ^ b2;

            float4 w0 = *(float4*)&Wb[z0 * LDW + u4];
            float4 w1 = *(float4*)&Wb[z1 * LDW + u4];
            float4 w2 = *(float4*)&Wb[z2 * LDW + u4];
            float4 w3 = *(float4*)&Wb[z3 * LDW + u4];
            float4 v0 = *(float4*)&VT[z0 * LDW + u4];
            float4 v1 = *(float4*)&VT[z1 * LDW + u4];
            float4 v2 = *(float4*)&VT[z2 * LDW + u4];
            float4 v3 = *(float4*)&VT[z3 * LDW + u4];
            float n0 = norms[z0], n1 = norms[z1], n2 = norms[z2], n3 = norms[z3];

            // sub-round mask b1: (0,1),(2,3); mask b2: (0,2),(1,3); mask b1^b2: (0,3),(1,2)
            jrot(w0, w1, v0, v1, n0, n1);  jrot(w2, w3, v2, v3, n2, n3);
            jrot(w0, w2, v0, v2, n0, n2);  jrot(w1, w3, v1, v3, n1, n3);
            jrot(w0, w3, v0, v3, n0, n3);  jrot(w1, w2, v1, v2, n1, n2);

            *(float4*)&Wb[z0 * LDW + u4] = w0;
            *(float4*)&Wb[z1 * LDW + u4] = w1;
            *(float4*)&Wb[z2 * LDW + u4] = w2;
            *(float4*)&Wb[z3 * LDW + u4] = w3;
            *(float4*)&VT[z0 * LDW + u4] = v0;
            *(float4*)&VT[z1 * LDW + u4] = v1;
            *(float4*)&VT[z2 * LDW + u4] = v2;
            *(float4*)&VT[z3 * LDW + u4] = v3;
            if (u == 0) {
                norms[z0] = n0; norms[z1] = n1; norms[z2] = n2; norms[z3] = n3;
            }
            __syncthreads();               // one barrier per 3 fused rounds
        }
    }

    // ---- eigenvalues: exact row norm^2 of W = lambda_k; store log ----
    #pragma unroll
    for (int i = 0; i < 4; ++i) {
        int r = (G << 2) + i;
        float4 x = *(float4*)&Wb[r * LDW + u4];
        float nn = red16(x.x * x.x + x.y * x.y + x.z * x.z + x.w * x.w);
        if (u == 0) norms[r] = logf(nn);
    }
    __syncthreads();

    // ---- Wb <- VT scaled rowwise by log(lambda) ----
    for (int e = t; e < 1024; e += TPB) {
        int row = e >> 4, col = (e & 15) << 2;
        float lwk = norms[row];
        float4 v = *(const float4*)&VT[row * LDW + col];
        v.x *= lwk; v.y *= lwk; v.z *= lwk; v.w *= lwk;
        *(float4*)&Wb[row * LDW + col] = v;
    }
    __syncthreads();

    // ---- upper-tri output: logm[i][j] = sum_k lw_k * VT[k][i] * VT[k][j] ----
    float* __restrict__ outb = out + (size_t)b * NTRI;
    for (int o = t; o < NTRI; o += TPB) {
        int i = (int)((129.0f - sqrtf(16641.0f - 8.0f * (float)o)) * 0.5f);
        while (i > 0 && i * (129 - i) / 2 > o) --i;
        while ((i + 1) * (129 - (i + 1)) / 2 <= o) ++i;
        int j = i + (o - i * (129 - i) / 2);

        float acc = 0.0f;
        #pragma unroll
        for (int k = 0; k < 64; ++k)
            acc = fmaf(Wb[k * LDW + i], VT[k * LDW + j], acc);
        outb[o] = acc;
    }
}

extern "C" void kernel_launch(void* const* d_in, const int* in_sizes, int n_in,
                              void* d_out, int out_size, void* d_ws, size_t ws_size,
                              hipStream_t stream) {
    const float* in = (const float*)d_in[0];
    float* out = (float*)d_out;
    int nmat = in_sizes[0] / 4096;    // 8192
    spd_logm_kernel<<<nmat, TPB, 0, stream>>>(in, out);
}

// Round 7
// 2947.716 us; speedup vs baseline: 6.7989x; 1.2829x over previous
//
#include <hip/hip_runtime.h>
#include <cmath>

#define TPB    256
#define SWEEPS 6
#define NTRI   2080      // 64*65/2
#define LDW    68        // row stride (floats): 16B-aligned rows, verified in R6

typedef float v4f __attribute__((ext_vector_type(4)));

// 21 XOR-closed triples {b1, b2, b1^b2} covering masks 1..63 — verified R6.
__constant__ int TB1[21] = {58,53,41,17,34,32,13,26,52,43,37,35,18,36,20,40,44,38,54,47,33};
__constant__ int TH1[21] = { 5, 5, 5, 4, 5, 5, 3, 4, 5, 5, 5, 5, 4, 5, 4, 5, 5, 5, 5, 5, 5};
__constant__ int TB2[21] = { 1, 2, 4, 8,16, 7, 3, 6,12,24,21, 9, 5,10,11,22,19,27,15,30,29};
__constant__ int TH2[21] = { 0, 1, 2, 3, 4, 2, 1, 2, 3, 4, 4, 3, 2, 3, 3, 4, 4, 4, 3, 4, 4};

__device__ __forceinline__ int rfl(int x) { return __builtin_amdgcn_readfirstlane(x); }

template<int CTRL>
__device__ __forceinline__ float dppf(float x) {
    return __int_as_float(__builtin_amdgcn_update_dpp(0, __float_as_int(x), CTRL, 0xf, 0xf, true));
}
// sum across 16-lane DPP row, broadcast to all 16 lanes (verified R6)
__device__ __forceinline__ float red16(float x) {
    x += dppf<0x124>(x);   // row_ror:4
    x += dppf<0x128>(x);   // row_ror:8
    x += dppf<0xB1>(x);    // quad_perm [1,0,3,2]
    x += dppf<0x4E>(x);    // quad_perm [2,3,0,1]
    return x;
}

#if __has_builtin(__builtin_elementwise_fma)
__device__ __forceinline__ v4f v4fma(v4f a, v4f b, v4f c) { return __builtin_elementwise_fma(a, b, c); }
#else
__device__ __forceinline__ v4f v4fma(v4f a, v4f b, v4f c) {
    v4f r; r.x=fmaf(a.x,b.x,c.x); r.y=fmaf(a.y,b.y,c.y); r.z=fmaf(a.z,b.z,c.z); r.w=fmaf(a.w,b.w,c.w); return r;
}
#endif

// One Jacobi rotation on register-resident W rows (no VT). Angle math = R4/R6 verified.
__device__ __forceinline__ void jrot2(v4f& wp, v4f& wq, float& np, float& nq) {
    v4f pr = wp * wq;
    float apq = red16(pr.x + pr.y + pr.z + pr.w);
    float tau = (nq - np) * 0.5f * __builtin_amdgcn_rcpf(apq);
    float den = fabsf(tau) + sqrtf(fmaf(tau, tau, 1.f));
    float tt  = copysignf(__builtin_amdgcn_rcpf(den), tau);
    tt = (fabsf(apq) < 1e-30f) ? 0.f : tt;
    float c = __builtin_amdgcn_rsqf(fmaf(tt, tt, 1.f));
    float s = tt * c;
    v4f cc = {c,c,c,c}, ss = {s,s,s,s};
    v4f wa = wp;
    wp = v4fma(cc, wp, -(ss * wq));   // c*wp - s*wq
    wq = v4fma(cc, wq,  (ss * wa));   // c*wq + s*wa
    np = fmaf(-tt, apq, np);
    nq = fmaf( tt, apq, nq);
}

__global__ __launch_bounds__(TPB) void spd_logm_kernel(const float* __restrict__ in,
                                                       float* __restrict__ out) {
    __shared__ __align__(16) float S[2 * 64 * LDW];   // [ W | Lc ]
    __shared__ __align__(16) float norms[64];         // row norm^2 -> log(lambda)
    float* __restrict__ Wb = S;
    float* __restrict__ Lc = S + 64 * LDW;

    const int b    = blockIdx.x;
    const int t    = threadIdx.x;
    const int lane = t & 63;
    const int w    = rfl(t >> 6);   // wave id (SGPR)
    const int G    = t >> 4;        // 16-lane group 0..15 (one 4-row coset)
    const int u    = t & 15;
    const int u4   = u << 2;

    // ---- load A (b128) ----
    const float4* __restrict__ in4 = (const float4*)(in + (size_t)b * 4096);
    for (int e = t; e < 1024; e += TPB) {
        int row = e >> 4, col = (e & 15) << 2;
        *(float4*)&Wb[row * LDW + col] = in4[e];
    }
    __syncthreads();

    // ---- Cholesky in place (verified R4/R6) ----
    for (int k = 0; k < 64; ++k) {
        if (w == 0) {
            float wkk = Wb[k * LDW + k];
            float rd  = __builtin_amdgcn_rsqf(wkk);
            Wb[lane * LDW + k] *= rd;
        }
        __syncthreads();
        float ck = Wb[lane * LDW + k];
        for (int i = k + 1 + w; i < 64; i += 4) {
            float aik = __shfl(ck, i, 64);
            if (lane > k) Wb[i * LDW + lane] -= aik * ck;
        }
        __syncthreads();
    }
    for (int e = t; e < 4096; e += TPB) {              // zero strict upper
        int r = e >> 6, c = e & 63;
        if (c > r) Wb[r * LDW + c] = 0.f;
    }
    __syncthreads();
    // keep a copy of L for the final triangular solve
    for (int e = t; e < 1088; e += TPB)                // 64*68/4 float4s (pads harmless)
        ((float4*)Lc)[e] = ((const float4*)Wb)[e];
    __syncthreads();

    // ---- one-sided Jacobi on rows of L (no VT accumulation) ----
    for (int sweep = 0; sweep < SWEEPS; ++sweep) {
        #pragma unroll
        for (int i = 0; i < 4; ++i) {                  // exact norm^2 refresh
            int r = ((t >> 4) << 2) + i;
            v4f x = *(v4f*)&Wb[r * LDW + u4];
            v4f p = x * x;
            float nn = red16(p.x + p.y + p.z + p.w);
            if (u == 0) norms[r] = nn;
        }
        __syncthreads();

        for (int j = 0; j < 21; ++j) {
            const int b1 = TB1[j], h1 = TH1[j], b2 = TB2[j], h2 = TH2[j];
            int m  = (G & ((1 << h2) - 1)) | ((G >> h2) << (h2 + 1));
            int rp = (m & ((1 << h1) - 1)) | ((m >> h1) << (h1 + 1));
            const int z0 = rp, z1 = rp ^ b1, z2 = rp ^ b2, z3 = z1 ^ b2;

            v4f w0 = *(v4f*)&Wb[z0 * LDW + u4];
            v4f w1 = *(v4f*)&Wb[z1 * LDW + u4];
            v4f w2 = *(v4f*)&Wb[z2 * LDW + u4];
            v4f w3 = *(v4f*)&Wb[z3 * LDW + u4];
            float n0 = norms[z0], n1 = norms[z1], n2 = norms[z2], n3 = norms[z3];

            jrot2(w0, w1, n0, n1);  jrot2(w2, w3, n2, n3);
            jrot2(w0, w2, n0, n2);  jrot2(w1, w3, n1, n3);
            jrot2(w0, w3, n0, n3);  jrot2(w1, w2, n1, n2);

            *(v4f*)&Wb[z0 * LDW + u4] = w0;
            *(v4f*)&Wb[z1 * LDW + u4] = w1;
            *(v4f*)&Wb[z2 * LDW + u4] = w2;
            *(v4f*)&Wb[z3 * LDW + u4] = w3;
            if (u == 0) { norms[z0] = n0; norms[z1] = n1; norms[z2] = n2; norms[z3] = n3; }
            __syncthreads();
        }
    }

    // ---- eigenvalues: lambda_k = ||row k||^2 (exact), store log ----
    #pragma unroll
    for (int i = 0; i < 4; ++i) {
        int r = ((t >> 4) << 2) + i;
        v4f x = *(v4f*)&Wb[r * LDW + u4];
        v4f p = x * x;
        float nn = red16(p.x + p.y + p.z + p.w);
        if (u == 0) norms[r] = logf(nn);
    }
    __syncthreads();

    // ---- transpose Wb in place: Wb <- L~^T (the RHS of the solve) ----
    for (int e = t; e < 4096; e += TPB) {
        int i = e >> 6, jj = e & 63;
        if (i < jj) {
            float a2 = Wb[i * LDW + jj], b2 = Wb[jj * LDW + i];
            Wb[i * LDW + jj] = b2;  Wb[jj * LDW + i] = a2;
        }
    }
    __syncthreads();

    // ---- back-substitution: L^T X = L~^T in place (X = Q^T, rows of Q = eigvecs) ----
    {
        const int c = lane;
        for (int j = 63; j > 0; --j) {
            if (w == 0) {
                float dj = Lc[j * LDW + j];
                Wb[j * LDW + c] *= __builtin_amdgcn_rcpf(dj);
            }
            __syncthreads();
            float xc = Wb[j * LDW + c];
            for (int i = j - 1 - w; i >= 0; i -= 4) {
                float lji = Lc[j * LDW + i];            // lane-uniform -> broadcast
                Wb[i * LDW + c] = fmaf(-lji, xc, Wb[i * LDW + c]);
            }
            __syncthreads();
        }
        if (w == 0) Wb[c] *= __builtin_amdgcn_rcpf(Lc[0]);
        __syncthreads();
    }

    // ---- Lc <- X scaled columnwise by lw_k (SX[a][k] = lw_k * X[a][k]) ----
    for (int e = t; e < 1024; e += TPB) {
        int row = e >> 4, k0 = (e & 15) << 2;
        v4f x  = *(v4f*)&Wb[row * LDW + k0];
        v4f lw = *(v4f*)&norms[k0];
        *(v4f*)&Lc[row * LDW + k0] = x * lw;
    }
    __syncthreads();

    // ---- upper-tri output: logm[a][b] = sum_k SX[a][k] * X[b][k] ----
    float* __restrict__ outb = out + (size_t)b * NTRI;
    for (int o = t; o < NTRI; o += TPB) {
        int i = (int)((129.0f - sqrtf(16641.0f - 8.0f * (float)o)) * 0.5f);
        while (i > 0 && i * (129 - i) / 2 > o) --i;
        while ((i + 1) * (129 - (i + 1)) / 2 <= o) ++i;
        int jj = i + (o - i * (129 - i) / 2);

        v4f acc4 = {0.f, 0.f, 0.f, 0.f};
        #pragma unroll
        for (int k = 0; k < 16; ++k) {
            v4f sx = *(v4f*)&Lc[i * LDW + (k << 2)];
            v4f xx = *(v4f*)&Wb[jj * LDW + (k << 2)];
            acc4 = v4fma(sx, xx, acc4);
        }
        outb[o] = acc4.x + acc4.y + acc4.z + acc4.w;
    }
}

extern "C" void kernel_launch(void* const* d_in, const int* in_sizes, int n_in,
                              void* d_out, int out_size, void* d_ws, size_t ws_size,
                              hipStream_t stream) {
    const float* in = (const float*)d_in[0];
    float* out = (float*)d_out;
    int nmat = in_sizes[0] / 4096;    // 8192
    spd_logm_kernel<<<nmat, TPB, 0, stream>>>(in, out);
}